// Round 4
// baseline (211.590 us; speedup 1.0000x reference)
//
#include <hip/hip_runtime.h>
#include <hip/hip_bf16.h>
#include <stdint.h>

typedef unsigned int u32;
typedef unsigned long long u64;

#define K_SEL 512
#define NBINS 4096
#define CAP 8192
#define SCORE_THR 0.05f
#define NMS_THR 0.5f
#define MAXROWS 512

__device__ __forceinline__ u32 fkey(float x) {
  u32 u = __float_as_uint(x);
  return u ^ ((u32)((int)u >> 31) | 0x80000000u);
}
__device__ __forceinline__ float fkey_inv(u32 k) {
  u32 u = (k & 0x80000000u) ? (k ^ 0x80000000u) : ~k;
  return __uint_as_float(u);
}

// K1a: per-anchor max logit -> sortable key (pure streaming, no histogram)
__global__ __launch_bounds__(256) void k_max(const float* __restrict__ logits,
                                             u32* __restrict__ skey, int N,
                                             int C) {
  int b = blockIdx.y;
  int n0 = blockIdx.x * MAXROWS;
  int nrow = min(MAXROWS, N - n0);
  __shared__ __align__(16) float tile[MAXROWS * 15];
  const float* src = logits + ((size_t)b * N + n0) * C;
  int tot = nrow * C;
  if (((tot & 3) == 0) && ((((size_t)src) & 15) == 0)) {
    const float4* s4 = (const float4*)src;
    float4* t4 = (float4*)tile;
    int n4 = tot >> 2;
    for (int i = threadIdx.x; i < n4; i += 256) t4[i] = s4[i];
  } else {
    for (int i = threadIdx.x; i < tot; i += 256) tile[i] = src[i];
  }
  __syncthreads();
  for (int r = threadIdx.x; r < nrow; r += 256) {
    const float* row = tile + r * 15;
    float mv = row[0];
    for (int c = 1; c < 15; c++) mv = fmaxf(mv, row[c]);
    skey[(size_t)b * N + n0 + r] = fkey(mv);
  }
}

// K1b: histogram of key top-12 bits (amortized LDS hist)
__global__ __launch_bounds__(256) void k_hist(const u32* __restrict__ skey,
                                              u32* __restrict__ hist, int N) {
  int b = blockIdx.y;
  __shared__ u32 sh[NBINS];
  for (int i = threadIdx.x; i < NBINS; i += 256) sh[i] = 0;
  __syncthreads();
  const u32* sb = skey + (size_t)b * N;
  for (int i = blockIdx.x * 256 + threadIdx.x; i < N; i += gridDim.x * 256)
    atomicAdd(&sh[sb[i] >> 20], 1u);
  __syncthreads();
  u32* hb = hist + (size_t)b * NBINS;
  for (int i = threadIdx.x; i < NBINS; i += 256) {
    u32 v = sh[i];
    if (v) atomicAdd(&hb[i], v);
  }
}

// K2: find cutoff bin T = max{bin : suffix_count(bin) >= K_SEL}
__global__ __launch_bounds__(256) void k_cutoff(const u32* __restrict__ hist,
                                                u32* __restrict__ cutT) {
  int b = blockIdx.x;
  int t = threadIdx.x;
  u32 h[16];
  u32 s = 0;
  const u32* hb = hist + (size_t)b * NBINS;
  for (int i = 0; i < 16; i++) { h[i] = hb[t * 16 + i]; s += h[i]; }
  __shared__ u32 cs[256];
  cs[t] = s;
  __syncthreads();
  for (int off = 1; off < 256; off <<= 1) {
    u32 add = (t + off < 256) ? cs[t + off] : 0;
    __syncthreads();
    cs[t] += add;
    __syncthreads();
  }
  u32 run = (t < 255) ? cs[t + 1] : 0;  // suffix over later chunks
  for (int i = 15; i >= 0; i--) {
    u32 sfx = run + h[i];
    if (run < (u32)K_SEL && sfx >= (u32)K_SEL) cutT[b] = (u32)(t * 16 + i);
    run = sfx;
  }
}

// K3: compact candidates with bin >= cutT
__global__ __launch_bounds__(256) void k_compact(
    const u32* __restrict__ skey, const u32* __restrict__ cutT,
    u64* __restrict__ cand, u32* __restrict__ cnt, int N) {
  int b = blockIdx.y;
  int n = blockIdx.x * 256 + threadIdx.x;
  if (n >= N) return;
  u32 key = skey[(size_t)b * N + n];
  if ((key >> 20) >= cutT[b]) {
    u32 pos = atomicAdd(&cnt[b], 1u);
    if (pos < CAP) cand[(size_t)b * CAP + pos] = ((u64)key << 32) | (u32)(~(u32)n);
  }
}

// K4: exact rank by counting (keys unique) -> sel[rank] for rank < K
__global__ __launch_bounds__(256) void k_rank(const u64* __restrict__ cand,
                                              const u32* __restrict__ cnt,
                                              u64* __restrict__ sel) {
  int b = blockIdx.y;
  int M = (int)min(cnt[b], (u32)CAP);
  if (blockIdx.x * 256 >= (u32)M) return;
  int m = blockIdx.x * 256 + threadIdx.x;
  u64 my = (m < M) ? cand[(size_t)b * CAP + m] : 0ull;
  int rank = 0;
  __shared__ u64 t[256];
  for (int j0 = 0; j0 < M; j0 += 256) {
    int j = j0 + threadIdx.x;
    t[threadIdx.x] = (j < M) ? cand[(size_t)b * CAP + j] : 0ull;
    __syncthreads();
    int lim = min(256, M - j0);
    for (int jj = 0; jj < lim; jj++) rank += (t[jj] > my) ? 1 : 0;
    __syncthreads();
  }
  if (m < M && rank < K_SEL) sel[b * K_SEL + rank] = my;
}

// K5: decode boxes, labels, scores, valid mask, corners/areas/radii
__global__ __launch_bounds__(256) void k_decode(
    const float* __restrict__ logits, const float* __restrict__ deltas,
    const float* __restrict__ anchors, const u64* __restrict__ sel,
    float* __restrict__ out, float* __restrict__ corners,
    float* __restrict__ areas, float* __restrict__ rad,
    u64* __restrict__ validw, int N, int C, int off_scores, int off_labels,
    int BK) {
  int g = blockIdx.x * 256 + threadIdx.x;
  if (g >= BK) return;
  int b = g >> 9;  // K_SEL == 512
  u64 s = sel[g];
  u32 key = (u32)(s >> 32);
  int idx = (int)(~(u32)s);
  float ml = fkey_inv(key);
  float score = 1.0f / (1.0f + expf(-ml));
  const float* lr = logits + ((size_t)b * N + idx) * C;
  float bv = lr[0];
  int lab = 0;
  for (int c = 1; c < C; c++) {
    float v = lr[c];
    if (v > bv) { bv = v; lab = c; }
  }
  const float* ar = anchors + (size_t)idx * 5;
  const float* dr = deltas + ((size_t)b * N + idx) * 5;
  float ax = ar[0], ay = ar[1], aw = ar[2], ah = ar[3], aa = ar[4];
  float dx = dr[0], dy = dr[1], dwv = dr[2], dhv = dr[3], da = dr[4];
  float px = ax + dx * aw;
  float py = ay + dy * ah;
  float pw = aw * expf(fminf(fmaxf(dwv, -4.0f), 4.0f));
  float ph = ah * expf(fminf(fmaxf(dhv, -4.0f), 4.0f));
  float pa = aa + da * 57.295779513082323f;
  float* ob = out + (size_t)g * 5;
  ob[0] = px; ob[1] = py; ob[2] = pw; ob[3] = ph; ob[4] = pa;
  out[off_scores + g] = score;
  out[off_labels + g] = (float)lab;
  bool valid = score > SCORE_THR;
  u64 bal = __ballot(valid);
  if ((threadIdx.x & 63) == 0) validw[g >> 6] = bal;
  float t = pa * 0.017453292519943295f;
  float cc = cosf(t), sn = sinf(t);
  float hx = pw * 0.5f, hy = ph * 0.5f;
  float* cp = corners + (size_t)g * 8;
  cp[0] = px + cc * (-hx) - sn * (-hy);
  cp[1] = py + sn * (-hx) + cc * (-hy);
  cp[2] = px + cc * (hx) - sn * (-hy);
  cp[3] = py + sn * (hx) + cc * (-hy);
  cp[4] = px + cc * (hx) - sn * (hy);
  cp[5] = py + sn * (hx) + cc * (hy);
  cp[6] = px + cc * (-hx) - sn * (hy);
  cp[7] = py + sn * (-hx) + cc * (hy);
  areas[g] = pw * ph;
  rad[g] = 0.5f * sqrtf(pw * pw + ph * ph);
}

// K6a: quick-reject all pairs, ballot-compact survivors into dense list
__global__ __launch_bounds__(256) void k_prefilter(
    const float* __restrict__ boxes, const float* __restrict__ rad,
    const float* __restrict__ areas, u32* __restrict__ pairlist,
    u32* __restrict__ paircnt) {
  int b = blockIdx.y;
  int q = blockIdx.x * 256 + threadIdx.x;
  int i = q >> 9, j = q & (K_SEL - 1);
  bool ok = (j > i);
  if (ok) {
    int gi = b * K_SEL + i, gj = b * K_SEL + j;
    float ddx = boxes[(size_t)gi * 5 + 0] - boxes[(size_t)gj * 5 + 0];
    float ddy = boxes[(size_t)gi * 5 + 1] - boxes[(size_t)gj * 5 + 1];
    float rr = rad[gi] + rad[gj];
    float d2 = ddx * ddx + ddy * ddy;
    ok = !(d2 > rr * rr * 1.0001f);
    if (ok) {
      float ai = areas[gi], aj = areas[gj];
      float mnA = fminf(ai, aj), mxA = fmaxf(ai, aj);
      ok = !(2.0f * mnA < 0.999f * mxA);
    }
  }
  u64 m = __ballot(ok);
  int lane = threadIdx.x & 63;
  u32 base = 0;
  if (lane == 0 && m) base = atomicAdd(paircnt, (u32)__popcll(m));
  base = (u32)__shfl((int)base, 0, 64);
  if (ok) {
    u32 r = (u32)__popcll(m & ((1ull << lane) - 1ull));
    pairlist[base + r] = ((u32)b << 18) | ((u32)i << 9) | (u32)j;
  }
}

// K6b: exact rotated IoU clip on survivors only, fully register-resident
__global__ __launch_bounds__(256) void k_clip(
    const u32* __restrict__ pairlist, const u32* __restrict__ paircnt,
    const float* __restrict__ corners, const float* __restrict__ areas,
    u64* __restrict__ sup) {
  u32 M = paircnt[0];
  for (u32 t = blockIdx.x * 256 + threadIdx.x; t < M; t += gridDim.x * 256) {
    u32 pk = pairlist[t];
    int b = (int)(pk >> 18);
    int i = (int)((pk >> 9) & 511u);
    int j = (int)(pk & 511u);
    int gi = b * K_SEL + i, gj = b * K_SEL + j;
    const float* ci = corners + (size_t)gi * 8;
    const float* cj = corners + (size_t)gj * 8;
    float X[8], Y[8], bx[4], by[4];
#pragma unroll
    for (int m = 0; m < 4; m++) {
      X[m] = ci[2 * m]; Y[m] = ci[2 * m + 1];
      X[m + 4] = 0.f; Y[m + 4] = 0.f;
      bx[m] = cj[2 * m]; by[m] = cj[2 * m + 1];
    }
    int cnt = 4;
#pragma unroll
    for (int e = 0; e < 4; e++) {
      float axp = bx[e], ayp = by[e];
      float ex = bx[(e + 1) & 3] - axp, ey = by[(e + 1) & 3] - ayp;
      float d[8];
#pragma unroll
      for (int m = 0; m < 8; m++)
        d[m] = ex * (Y[m] - ayp) - ey * (X[m] - axp);
      float NX[8], NY[8];
#pragma unroll
      for (int s = 0; s < 8; s++) { NX[s] = 0.f; NY[s] = 0.f; }
      int oc = 0;
#pragma unroll
      for (int m = 0; m < 8; m++) {
        bool act = (m < cnt);
        bool isLast = (m + 1 == cnt);
        float dn = isLast ? d[0] : d[(m + 1) & 7];
        float xn = isLast ? X[0] : X[(m + 1) & 7];
        float yn = isLast ? Y[0] : Y[(m + 1) & 7];
        bool cin = (d[m] >= 0.f), nin = (dn >= 0.f);
        bool e1 = act && cin;
        bool e2 = act && (cin != nin);
#pragma unroll
        for (int s = 0; s < 8; s++) {
          bool w = e1 && (oc == s);
          NX[s] = w ? X[m] : NX[s];
          NY[s] = w ? Y[m] : NY[s];
        }
        oc += e1 ? 1 : 0;
        float den = d[m] - dn;
        float dd = (fabsf(den) < 1e-9f) ? 1e-9f : den;
        float tt = d[m] / dd;
        float ix = X[m] + tt * (xn - X[m]);
        float iy = Y[m] + tt * (yn - Y[m]);
#pragma unroll
        for (int s = 0; s < 8; s++) {
          bool w = e2 && (oc == s);
          NX[s] = w ? ix : NX[s];
          NY[s] = w ? iy : NY[s];
        }
        oc += e2 ? 1 : 0;
      }
      cnt = oc;
#pragma unroll
      for (int m = 0; m < 8; m++) { X[m] = NX[m]; Y[m] = NY[m]; }
    }
    float sum = 0.f;
#pragma unroll
    for (int m = 0; m < 8; m++) {
      bool act = (m < cnt);
      bool isLast = (m + 1 == cnt);
      float xn = isLast ? X[0] : X[(m + 1) & 7];
      float yn = isLast ? Y[0] : Y[(m + 1) & 7];
      float cr = X[m] * yn - Y[m] * xn;
      sum += act ? cr : 0.f;
    }
    float inter = (cnt >= 3) ? 0.5f * fabsf(sum) : 0.f;
    float ai = areas[gi], aj = areas[gj];
    float uni = ai + aj - inter;
    float iou = inter / fmaxf(uni, 1e-6f);
    if (iou > NMS_THR)
      atomicOr(&sup[((size_t)b * K_SEL + i) * 8 + (j >> 6)], 1ull << (j & 63));
  }
}

// K7: sequential NMS sweep, replicated 512-bit state in registers, no shuffles
#define GLUE2(a, b) a##b
#define GLUE(a, b) GLUE2(a, b)

#define NMS_STEP(BUF, Ii, cc)                                              \
  {                                                                        \
    int bit_ = (Ii) & 63;                                                  \
    u64 live_ = ((vv >> bit_) & ~(rw >> bit_)) & 1ull;                     \
    u64 m_ = (u64)0 - live_;                                               \
    rem0 |= GLUE(BUF, 0) & m_; rem1 |= GLUE(BUF, 1) & m_;                  \
    rem2 |= GLUE(BUF, 2) & m_; rem3 |= GLUE(BUF, 3) & m_;                  \
    rem4 |= GLUE(BUF, 4) & m_; rem5 |= GLUE(BUF, 5) & m_;                  \
    rem6 |= GLUE(BUF, 6) & m_; rem7 |= GLUE(BUF, 7) & m_;                  \
    rw |= GLUE(BUF, cc) & m_;                                              \
    km |= live_ << bit_;                                                   \
    int pr_ = ((Ii) + 4) & (K_SEL - 1);                                    \
    GLUE(BUF, 0) = ls[pr_ * 8 + 0]; GLUE(BUF, 1) = ls[pr_ * 8 + 1];        \
    GLUE(BUF, 2) = ls[pr_ * 8 + 2]; GLUE(BUF, 3) = ls[pr_ * 8 + 3];        \
    GLUE(BUF, 4) = ls[pr_ * 8 + 4]; GLUE(BUF, 5) = ls[pr_ * 8 + 5];        \
    GLUE(BUF, 6) = ls[pr_ * 8 + 6]; GLUE(BUF, 7) = ls[pr_ * 8 + 7];        \
  }

#define NMS_CHUNK(cc)                                                      \
  {                                                                        \
    u64 vv = GLUE(va, cc);                                                 \
    u64 rw = GLUE(rem, cc);                                                \
    u64 km = 0;                                                            \
    for (int g = 0; g < 16; ++g) {                                         \
      int i0 = (cc)*64 + g * 4;                                            \
      NMS_STEP(A, i0 + 0, cc)                                              \
      NMS_STEP(B, i0 + 1, cc)                                              \
      NMS_STEP(C, i0 + 2, cc)                                              \
      NMS_STEP(D, i0 + 3, cc)                                              \
    }                                                                      \
    ko[(cc)*64 + lane] = (float)((km >> lane) & 1ull);                     \
  }

__global__ __launch_bounds__(256) void k_nms(const u64* __restrict__ sup,
                                             const u64* __restrict__ validw,
                                             float* __restrict__ keep_out) {
  int b = blockIdx.x;
  __shared__ u64 ls[K_SEL * 8];
  const u64* sb = sup + (size_t)b * K_SEL * 8;
  {
    const ulonglong2* s2 = (const ulonglong2*)sb;
    ulonglong2* l2 = (ulonglong2*)ls;
    for (int k = threadIdx.x; k < K_SEL * 4; k += 256) l2[k] = s2[k];
  }
  __syncthreads();
  if (threadIdx.x >= 64) return;
  int lane = threadIdx.x;
  const u64* vb = validw + (size_t)b * 8;
  u64 va0 = vb[0], va1 = vb[1], va2 = vb[2], va3 = vb[3];
  u64 va4 = vb[4], va5 = vb[5], va6 = vb[6], va7 = vb[7];
  u64 rem0 = 0, rem1 = 0, rem2 = 0, rem3 = 0;
  u64 rem4 = 0, rem5 = 0, rem6 = 0, rem7 = 0;
  u64 A0 = ls[0], A1 = ls[1], A2 = ls[2], A3 = ls[3];
  u64 A4 = ls[4], A5 = ls[5], A6 = ls[6], A7 = ls[7];
  u64 B0 = ls[8], B1 = ls[9], B2 = ls[10], B3 = ls[11];
  u64 B4 = ls[12], B5 = ls[13], B6 = ls[14], B7 = ls[15];
  u64 C0 = ls[16], C1 = ls[17], C2 = ls[18], C3 = ls[19];
  u64 C4 = ls[20], C5 = ls[21], C6 = ls[22], C7 = ls[23];
  u64 D0 = ls[24], D1 = ls[25], D2 = ls[26], D3 = ls[27];
  u64 D4 = ls[28], D5 = ls[29], D6 = ls[30], D7 = ls[31];
  float* ko = keep_out + b * K_SEL;
  NMS_CHUNK(0)
  NMS_CHUNK(1)
  NMS_CHUNK(2)
  NMS_CHUNK(3)
  NMS_CHUNK(4)
  NMS_CHUNK(5)
  NMS_CHUNK(6)
  NMS_CHUNK(7)
}

extern "C" void kernel_launch(void* const* d_in, const int* in_sizes, int n_in,
                              void* d_out, int out_size, void* d_ws,
                              size_t ws_size, hipStream_t stream) {
  const float* logits = (const float*)d_in[0];
  const float* deltas = (const float*)d_in[1];
  const float* anchors = (const float*)d_in[2];
  float* out = (float*)d_out;
  int N = in_sizes[2] / 5;
  int B = in_sizes[1] / (N * 5);
  int C = (int)((long long)in_sizes[0] / ((long long)B * N));
  int BK = B * K_SEL;

  char* ws = (char*)d_ws;
  size_t o_hist = 0;
  size_t o_cnt = o_hist + (size_t)B * NBINS * 4;
  size_t o_cut = o_cnt + 128;
  size_t o_sup = o_cnt + 256;
  size_t zero_end = o_sup + (size_t)B * K_SEL * 8 * 8;
  size_t o_skey = (zero_end + 255) & ~(size_t)255;
  size_t o_cand = (o_skey + (size_t)B * N * 4 + 255) & ~(size_t)255;
  size_t o_sel = (o_cand + (size_t)B * CAP * 8 + 255) & ~(size_t)255;
  size_t o_vw = (o_sel + (size_t)BK * 8 + 255) & ~(size_t)255;
  size_t o_corn = (o_vw + (size_t)B * 8 * 8 + 255) & ~(size_t)255;
  size_t o_area = (o_corn + (size_t)BK * 8 * 4 + 255) & ~(size_t)255;
  size_t o_rad = (o_area + (size_t)BK * 4 + 255) & ~(size_t)255;
  size_t o_pair = (o_rad + (size_t)BK * 4 + 255) & ~(size_t)255;

  u32* hist = (u32*)(ws + o_hist);
  u32* cnt = (u32*)(ws + o_cnt);
  u32* paircnt = (u32*)(ws + o_cnt + 64);
  u32* cutT = (u32*)(ws + o_cut);
  u64* sup = (u64*)(ws + o_sup);
  u32* skey = (u32*)(ws + o_skey);
  u64* cand = (u64*)(ws + o_cand);
  u64* sel = (u64*)(ws + o_sel);
  u64* validw = (u64*)(ws + o_vw);
  float* corners = (float*)(ws + o_corn);
  float* areas = (float*)(ws + o_area);
  float* rad = (float*)(ws + o_rad);
  u32* pairlist = (u32*)(ws + o_pair);

  hipMemsetAsync(d_ws, 0, zero_end, stream);

  int nbm = (N + MAXROWS - 1) / MAXROWS;
  int nb = (N + 255) / 256;
  k_max<<<dim3(nbm, B), 256, 0, stream>>>(logits, skey, N, C);
  k_hist<<<dim3(128, B), 256, 0, stream>>>(skey, hist, N);
  k_cutoff<<<B, 256, 0, stream>>>(hist, cutT);
  k_compact<<<dim3(nb, B), 256, 0, stream>>>(skey, cutT, cand, cnt, N);
  k_rank<<<dim3(CAP / 256, B), 256, 0, stream>>>(cand, cnt, sel);
  int off_scores = BK * 5, off_labels = BK * 6, off_keep = BK * 7;
  k_decode<<<(BK + 255) / 256, 256, 0, stream>>>(
      logits, deltas, anchors, sel, out, corners, areas, rad, validw, N, C,
      off_scores, off_labels, BK);
  k_prefilter<<<dim3(K_SEL * K_SEL / 256, B), 256, 0, stream>>>(
      out, rad, areas, pairlist, paircnt);
  k_clip<<<512, 256, 0, stream>>>(pairlist, paircnt, corners, areas, sup);
  k_nms<<<B, 256, 0, stream>>>(sup, validw, out + off_keep);
}

// Round 5
// 167.496 us; speedup vs baseline: 1.2633x; 1.2633x over previous
//
#include <hip/hip_runtime.h>
#include <hip/hip_bf16.h>
#include <stdint.h>

typedef unsigned int u32;
typedef unsigned long long u64;

#define K_SEL 512
#define NBINS 4096
#define CAP 8192
#define SCORE_THR 0.05f
#define NMS_THR 0.5f
#define MAXROWS 512

__device__ __forceinline__ u32 fkey(float x) {
  u32 u = __float_as_uint(x);
  return u ^ ((u32)((int)u >> 31) | 0x80000000u);
}
__device__ __forceinline__ float fkey_inv(u32 k) {
  u32 u = (k & 0x80000000u) ? (k ^ 0x80000000u) : ~k;
  return __uint_as_float(u);
}

// K1a: per-anchor max logit -> sortable key (pure streaming, no histogram)
__global__ __launch_bounds__(256) void k_max(const float* __restrict__ logits,
                                             u32* __restrict__ skey, int N,
                                             int C) {
  int b = blockIdx.y;
  int n0 = blockIdx.x * MAXROWS;
  int nrow = min(MAXROWS, N - n0);
  __shared__ __align__(16) float tile[MAXROWS * 15];
  const float* src = logits + ((size_t)b * N + n0) * C;
  int tot = nrow * C;
  if (((tot & 3) == 0) && ((((size_t)src) & 15) == 0)) {
    const float4* s4 = (const float4*)src;
    float4* t4 = (float4*)tile;
    int n4 = tot >> 2;
    for (int i = threadIdx.x; i < n4; i += 256) t4[i] = s4[i];
  } else {
    for (int i = threadIdx.x; i < tot; i += 256) tile[i] = src[i];
  }
  __syncthreads();
  for (int r = threadIdx.x; r < nrow; r += 256) {
    const float* row = tile + r * 15;
    float mv = row[0];
    for (int c = 1; c < 15; c++) mv = fmaxf(mv, row[c]);
    skey[(size_t)b * N + n0 + r] = fkey(mv);
  }
}

// K1b: histogram of key top-12 bits (amortized LDS hist)
__global__ __launch_bounds__(256) void k_hist(const u32* __restrict__ skey,
                                              u32* __restrict__ hist, int N) {
  int b = blockIdx.y;
  __shared__ u32 sh[NBINS];
  for (int i = threadIdx.x; i < NBINS; i += 256) sh[i] = 0;
  __syncthreads();
  const u32* sb = skey + (size_t)b * N;
  for (int i = blockIdx.x * 256 + threadIdx.x; i < N; i += gridDim.x * 256)
    atomicAdd(&sh[sb[i] >> 20], 1u);
  __syncthreads();
  u32* hb = hist + (size_t)b * NBINS;
  for (int i = threadIdx.x; i < NBINS; i += 256) {
    u32 v = sh[i];
    if (v) atomicAdd(&hb[i], v);
  }
}

// K2: find cutoff bin T = max{bin : suffix_count(bin) >= K_SEL}
__global__ __launch_bounds__(256) void k_cutoff(const u32* __restrict__ hist,
                                                u32* __restrict__ cutT) {
  int b = blockIdx.x;
  int t = threadIdx.x;
  u32 h[16];
  u32 s = 0;
  const u32* hb = hist + (size_t)b * NBINS;
  for (int i = 0; i < 16; i++) { h[i] = hb[t * 16 + i]; s += h[i]; }
  __shared__ u32 cs[256];
  cs[t] = s;
  __syncthreads();
  for (int off = 1; off < 256; off <<= 1) {
    u32 add = (t + off < 256) ? cs[t + off] : 0;
    __syncthreads();
    cs[t] += add;
    __syncthreads();
  }
  u32 run = (t < 255) ? cs[t + 1] : 0;  // suffix over later chunks
  for (int i = 15; i >= 0; i--) {
    u32 sfx = run + h[i];
    if (run < (u32)K_SEL && sfx >= (u32)K_SEL) cutT[b] = (u32)(t * 16 + i);
    run = sfx;
  }
}

// K3: compact candidates with bin >= cutT
__global__ __launch_bounds__(256) void k_compact(
    const u32* __restrict__ skey, const u32* __restrict__ cutT,
    u64* __restrict__ cand, u32* __restrict__ cnt, int N) {
  int b = blockIdx.y;
  int n = blockIdx.x * 256 + threadIdx.x;
  if (n >= N) return;
  u32 key = skey[(size_t)b * N + n];
  if ((key >> 20) >= cutT[b]) {
    u32 pos = atomicAdd(&cnt[b], 1u);
    if (pos < CAP) cand[(size_t)b * CAP + pos] = ((u64)key << 32) | (u32)(~(u32)n);
  }
}

// K4: exact rank by counting (keys unique) -> sel[rank] for rank < K
__global__ __launch_bounds__(256) void k_rank(const u64* __restrict__ cand,
                                              const u32* __restrict__ cnt,
                                              u64* __restrict__ sel) {
  int b = blockIdx.y;
  int M = (int)min(cnt[b], (u32)CAP);
  if (blockIdx.x * 256 >= (u32)M) return;
  int m = blockIdx.x * 256 + threadIdx.x;
  u64 my = (m < M) ? cand[(size_t)b * CAP + m] : 0ull;
  int rank = 0;
  __shared__ u64 t[256];
  for (int j0 = 0; j0 < M; j0 += 256) {
    int j = j0 + threadIdx.x;
    t[threadIdx.x] = (j < M) ? cand[(size_t)b * CAP + j] : 0ull;
    __syncthreads();
    int lim = min(256, M - j0);
    for (int jj = 0; jj < lim; jj++) rank += (t[jj] > my) ? 1 : 0;
    __syncthreads();
  }
  if (m < M && rank < K_SEL) sel[b * K_SEL + rank] = my;
}

// K5: decode boxes, labels, scores, valid mask, corners/areas/radii
__global__ __launch_bounds__(256) void k_decode(
    const float* __restrict__ logits, const float* __restrict__ deltas,
    const float* __restrict__ anchors, const u64* __restrict__ sel,
    float* __restrict__ out, float* __restrict__ corners,
    float* __restrict__ areas, float* __restrict__ rad,
    u64* __restrict__ validw, int N, int C, int off_scores, int off_labels,
    int BK) {
  int g = blockIdx.x * 256 + threadIdx.x;
  if (g >= BK) return;
  int b = g >> 9;  // K_SEL == 512
  u64 s = sel[g];
  u32 key = (u32)(s >> 32);
  int idx = (int)(~(u32)s);
  float ml = fkey_inv(key);
  float score = 1.0f / (1.0f + expf(-ml));
  const float* lr = logits + ((size_t)b * N + idx) * C;
  float bv = lr[0];
  int lab = 0;
  for (int c = 1; c < C; c++) {
    float v = lr[c];
    if (v > bv) { bv = v; lab = c; }
  }
  const float* ar = anchors + (size_t)idx * 5;
  const float* dr = deltas + ((size_t)b * N + idx) * 5;
  float ax = ar[0], ay = ar[1], aw = ar[2], ah = ar[3], aa = ar[4];
  float dx = dr[0], dy = dr[1], dwv = dr[2], dhv = dr[3], da = dr[4];
  float px = ax + dx * aw;
  float py = ay + dy * ah;
  float pw = aw * expf(fminf(fmaxf(dwv, -4.0f), 4.0f));
  float ph = ah * expf(fminf(fmaxf(dhv, -4.0f), 4.0f));
  float pa = aa + da * 57.295779513082323f;
  float* ob = out + (size_t)g * 5;
  ob[0] = px; ob[1] = py; ob[2] = pw; ob[3] = ph; ob[4] = pa;
  out[off_scores + g] = score;
  out[off_labels + g] = (float)lab;
  bool valid = score > SCORE_THR;
  u64 bal = __ballot(valid);
  if ((threadIdx.x & 63) == 0) validw[g >> 6] = bal;
  float t = pa * 0.017453292519943295f;
  float cc = cosf(t), sn = sinf(t);
  float hx = pw * 0.5f, hy = ph * 0.5f;
  float* cp = corners + (size_t)g * 8;
  cp[0] = px + cc * (-hx) - sn * (-hy);
  cp[1] = py + sn * (-hx) + cc * (-hy);
  cp[2] = px + cc * (hx) - sn * (-hy);
  cp[3] = py + sn * (hx) + cc * (-hy);
  cp[4] = px + cc * (hx) - sn * (hy);
  cp[5] = py + sn * (hx) + cc * (hy);
  cp[6] = px + cc * (-hx) - sn * (hy);
  cp[7] = py + sn * (-hx) + cc * (hy);
  areas[g] = pw * ph;
  rad[g] = 0.5f * sqrtf(pw * pw + ph * ph);
}

// K6a: quick-reject all pairs, per-wave segment compaction (NO shared atomics)
__global__ __launch_bounds__(256) void k_prefilter(
    const float* __restrict__ boxes, const float* __restrict__ rad,
    const float* __restrict__ areas, u32* __restrict__ pairlist,
    u32* __restrict__ segcnt) {
  int b = blockIdx.y;
  int q = blockIdx.x * 256 + threadIdx.x;
  int i = q >> 9, j = q & (K_SEL - 1);
  bool ok = (j > i);
  if (ok) {
    int gi = b * K_SEL + i, gj = b * K_SEL + j;
    float ddx = boxes[(size_t)gi * 5 + 0] - boxes[(size_t)gj * 5 + 0];
    float ddy = boxes[(size_t)gi * 5 + 1] - boxes[(size_t)gj * 5 + 1];
    float rr = rad[gi] + rad[gj];
    float d2 = ddx * ddx + ddy * ddy;
    ok = !(d2 > rr * rr * 1.0001f);
    if (ok) {
      float ai = areas[gi], aj = areas[gj];
      float mnA = fminf(ai, aj), mxA = fmaxf(ai, aj);
      ok = !(2.0f * mnA < 0.999f * mxA);
    }
  }
  u64 m = __ballot(ok);
  int lane = threadIdx.x & 63;
  int wseg = ((b * gridDim.x + blockIdx.x) << 2) + (threadIdx.x >> 6);
  if (ok) {
    u32 r = (u32)__popcll(m & ((1ull << lane) - 1ull));
    pairlist[((size_t)wseg << 6) + r] = ((u32)b << 18) | ((u32)i << 9) | (u32)j;
  }
  if (lane == 0) segcnt[wseg] = (u32)__popcll(m);
}

// K6b: exact rotated IoU clip, one wave per survivor segment
__global__ __launch_bounds__(256) void k_clip(
    const u32* __restrict__ pairlist, const u32* __restrict__ segcnt,
    const float* __restrict__ corners, const float* __restrict__ areas,
    u64* __restrict__ sup, int nseg) {
  int wid = (blockIdx.x * 256 + threadIdx.x) >> 6;
  int lane = threadIdx.x & 63;
  if (wid >= nseg) return;
  u32 wcnt = segcnt[wid];
  if (wcnt == 0) return;  // wave-uniform early exit
  if (lane >= (int)wcnt) return;
  u32 pk = pairlist[((size_t)wid << 6) + lane];
  int b = (int)(pk >> 18);
  int i = (int)((pk >> 9) & 511u);
  int j = (int)(pk & 511u);
  int gi = b * K_SEL + i, gj = b * K_SEL + j;
  const float* ci = corners + (size_t)gi * 8;
  const float* cj = corners + (size_t)gj * 8;
  float X[8], Y[8], bx[4], by[4];
#pragma unroll
  for (int m = 0; m < 4; m++) {
    X[m] = ci[2 * m]; Y[m] = ci[2 * m + 1];
    X[m + 4] = 0.f; Y[m + 4] = 0.f;
    bx[m] = cj[2 * m]; by[m] = cj[2 * m + 1];
  }
  int cnt = 4;
#pragma unroll
  for (int e = 0; e < 4; e++) {
    float axp = bx[e], ayp = by[e];
    float ex = bx[(e + 1) & 3] - axp, ey = by[(e + 1) & 3] - ayp;
    float d[8];
#pragma unroll
    for (int m = 0; m < 8; m++)
      d[m] = ex * (Y[m] - ayp) - ey * (X[m] - axp);
    float NX[8], NY[8];
#pragma unroll
    for (int s = 0; s < 8; s++) { NX[s] = 0.f; NY[s] = 0.f; }
    int oc = 0;
#pragma unroll
    for (int m = 0; m < 8; m++) {
      bool act = (m < cnt);
      bool isLast = (m + 1 == cnt);
      float dn = isLast ? d[0] : d[(m + 1) & 7];
      float xn = isLast ? X[0] : X[(m + 1) & 7];
      float yn = isLast ? Y[0] : Y[(m + 1) & 7];
      bool cin = (d[m] >= 0.f), nin = (dn >= 0.f);
      bool e1 = act && cin;
      bool e2 = act && (cin != nin);
#pragma unroll
      for (int s = 0; s < 8; s++) {
        bool w = e1 && (oc == s);
        NX[s] = w ? X[m] : NX[s];
        NY[s] = w ? Y[m] : NY[s];
      }
      oc += e1 ? 1 : 0;
      float den = d[m] - dn;
      float dd = (fabsf(den) < 1e-9f) ? 1e-9f : den;
      float tt = d[m] / dd;
      float ix = X[m] + tt * (xn - X[m]);
      float iy = Y[m] + tt * (yn - Y[m]);
#pragma unroll
      for (int s = 0; s < 8; s++) {
        bool w = e2 && (oc == s);
        NX[s] = w ? ix : NX[s];
        NY[s] = w ? iy : NY[s];
      }
      oc += e2 ? 1 : 0;
    }
    cnt = oc;
#pragma unroll
    for (int m = 0; m < 8; m++) { X[m] = NX[m]; Y[m] = NY[m]; }
  }
  float sum = 0.f;
#pragma unroll
  for (int m = 0; m < 8; m++) {
    bool act = (m < cnt);
    bool isLast = (m + 1 == cnt);
    float xn = isLast ? X[0] : X[(m + 1) & 7];
    float yn = isLast ? Y[0] : Y[(m + 1) & 7];
    float cr = X[m] * yn - Y[m] * xn;
    sum += act ? cr : 0.f;
  }
  float inter = (cnt >= 3) ? 0.5f * fabsf(sum) : 0.f;
  float ai = areas[gi], aj = areas[gj];
  float uni = ai + aj - inter;
  float iou = inter / fmaxf(uni, 1e-6f);
  if (iou > NMS_THR)
    atomicOr(&sup[((size_t)b * K_SEL + i) * 8 + (j >> 6)], 1ull << (j & 63));
}

// K7: sequential NMS sweep, replicated 512-bit state in registers, no shuffles
#define GLUE2(a, b) a##b
#define GLUE(a, b) GLUE2(a, b)

#define NMS_STEP(BUF, Ii, cc)                                              \
  {                                                                        \
    int bit_ = (Ii) & 63;                                                  \
    u64 live_ = ((vv >> bit_) & ~(rw >> bit_)) & 1ull;                     \
    u64 m_ = (u64)0 - live_;                                               \
    rem0 |= GLUE(BUF, 0) & m_; rem1 |= GLUE(BUF, 1) & m_;                  \
    rem2 |= GLUE(BUF, 2) & m_; rem3 |= GLUE(BUF, 3) & m_;                  \
    rem4 |= GLUE(BUF, 4) & m_; rem5 |= GLUE(BUF, 5) & m_;                  \
    rem6 |= GLUE(BUF, 6) & m_; rem7 |= GLUE(BUF, 7) & m_;                  \
    rw |= GLUE(BUF, cc) & m_;                                              \
    km |= live_ << bit_;                                                   \
    int pr_ = ((Ii) + 4) & (K_SEL - 1);                                    \
    GLUE(BUF, 0) = ls[pr_ * 8 + 0]; GLUE(BUF, 1) = ls[pr_ * 8 + 1];        \
    GLUE(BUF, 2) = ls[pr_ * 8 + 2]; GLUE(BUF, 3) = ls[pr_ * 8 + 3];        \
    GLUE(BUF, 4) = ls[pr_ * 8 + 4]; GLUE(BUF, 5) = ls[pr_ * 8 + 5];        \
    GLUE(BUF, 6) = ls[pr_ * 8 + 6]; GLUE(BUF, 7) = ls[pr_ * 8 + 7];        \
  }

#define NMS_CHUNK(cc)                                                      \
  {                                                                        \
    u64 vv = GLUE(va, cc);                                                 \
    u64 rw = GLUE(rem, cc);                                                \
    u64 km = 0;                                                            \
    for (int g = 0; g < 16; ++g) {                                         \
      int i0 = (cc)*64 + g * 4;                                            \
      NMS_STEP(A, i0 + 0, cc)                                              \
      NMS_STEP(B, i0 + 1, cc)                                              \
      NMS_STEP(C, i0 + 2, cc)                                              \
      NMS_STEP(D, i0 + 3, cc)                                              \
    }                                                                      \
    ko[(cc)*64 + lane] = (float)((km >> lane) & 1ull);                     \
  }

__global__ __launch_bounds__(256) void k_nms(const u64* __restrict__ sup,
                                             const u64* __restrict__ validw,
                                             float* __restrict__ keep_out) {
  int b = blockIdx.x;
  __shared__ u64 ls[K_SEL * 8];
  const u64* sb = sup + (size_t)b * K_SEL * 8;
  {
    const ulonglong2* s2 = (const ulonglong2*)sb;
    ulonglong2* l2 = (ulonglong2*)ls;
    for (int k = threadIdx.x; k < K_SEL * 4; k += 256) l2[k] = s2[k];
  }
  __syncthreads();
  if (threadIdx.x >= 64) return;
  int lane = threadIdx.x;
  const u64* vb = validw + (size_t)b * 8;
  u64 va0 = vb[0], va1 = vb[1], va2 = vb[2], va3 = vb[3];
  u64 va4 = vb[4], va5 = vb[5], va6 = vb[6], va7 = vb[7];
  u64 rem0 = 0, rem1 = 0, rem2 = 0, rem3 = 0;
  u64 rem4 = 0, rem5 = 0, rem6 = 0, rem7 = 0;
  u64 A0 = ls[0], A1 = ls[1], A2 = ls[2], A3 = ls[3];
  u64 A4 = ls[4], A5 = ls[5], A6 = ls[6], A7 = ls[7];
  u64 B0 = ls[8], B1 = ls[9], B2 = ls[10], B3 = ls[11];
  u64 B4 = ls[12], B5 = ls[13], B6 = ls[14], B7 = ls[15];
  u64 C0 = ls[16], C1 = ls[17], C2 = ls[18], C3 = ls[19];
  u64 C4 = ls[20], C5 = ls[21], C6 = ls[22], C7 = ls[23];
  u64 D0 = ls[24], D1 = ls[25], D2 = ls[26], D3 = ls[27];
  u64 D4 = ls[28], D5 = ls[29], D6 = ls[30], D7 = ls[31];
  float* ko = keep_out + b * K_SEL;
  NMS_CHUNK(0)
  NMS_CHUNK(1)
  NMS_CHUNK(2)
  NMS_CHUNK(3)
  NMS_CHUNK(4)
  NMS_CHUNK(5)
  NMS_CHUNK(6)
  NMS_CHUNK(7)
}

extern "C" void kernel_launch(void* const* d_in, const int* in_sizes, int n_in,
                              void* d_out, int out_size, void* d_ws,
                              size_t ws_size, hipStream_t stream) {
  const float* logits = (const float*)d_in[0];
  const float* deltas = (const float*)d_in[1];
  const float* anchors = (const float*)d_in[2];
  float* out = (float*)d_out;
  int N = in_sizes[2] / 5;
  int B = in_sizes[1] / (N * 5);
  int C = (int)((long long)in_sizes[0] / ((long long)B * N));
  int BK = B * K_SEL;
  int NPB = K_SEL * K_SEL / 256;      // pair-blocks per image
  int NSEG = B * NPB * 4;             // one segment per wave

  char* ws = (char*)d_ws;
  size_t o_hist = 0;
  size_t o_cnt = o_hist + (size_t)B * NBINS * 4;
  size_t o_sup = o_cnt + 256;
  size_t zero_end = o_sup + (size_t)B * K_SEL * 8 * 8;
  size_t o_cut = (zero_end + 255) & ~(size_t)255;
  size_t o_skey = (o_cut + 256 + 255) & ~(size_t)255;
  size_t o_cand = (o_skey + (size_t)B * N * 4 + 255) & ~(size_t)255;
  size_t o_sel = (o_cand + (size_t)B * CAP * 8 + 255) & ~(size_t)255;
  size_t o_vw = (o_sel + (size_t)BK * 8 + 255) & ~(size_t)255;
  size_t o_corn = (o_vw + (size_t)B * 8 * 8 + 255) & ~(size_t)255;
  size_t o_area = (o_corn + (size_t)BK * 8 * 4 + 255) & ~(size_t)255;
  size_t o_rad = (o_area + (size_t)BK * 4 + 255) & ~(size_t)255;
  size_t o_segc = (o_rad + (size_t)BK * 4 + 255) & ~(size_t)255;
  size_t o_pair = (o_segc + (size_t)NSEG * 4 + 255) & ~(size_t)255;

  u32* hist = (u32*)(ws + o_hist);
  u32* cnt = (u32*)(ws + o_cnt);
  u32* cutT = (u32*)(ws + o_cut);
  u64* sup = (u64*)(ws + o_sup);
  u32* skey = (u32*)(ws + o_skey);
  u64* cand = (u64*)(ws + o_cand);
  u64* sel = (u64*)(ws + o_sel);
  u64* validw = (u64*)(ws + o_vw);
  float* corners = (float*)(ws + o_corn);
  float* areas = (float*)(ws + o_area);
  float* rad = (float*)(ws + o_rad);
  u32* segcnt = (u32*)(ws + o_segc);
  u32* pairlist = (u32*)(ws + o_pair);

  hipMemsetAsync(d_ws, 0, zero_end, stream);

  int nbm = (N + MAXROWS - 1) / MAXROWS;
  int nb = (N + 255) / 256;
  k_max<<<dim3(nbm, B), 256, 0, stream>>>(logits, skey, N, C);
  k_hist<<<dim3(128, B), 256, 0, stream>>>(skey, hist, N);
  k_cutoff<<<B, 256, 0, stream>>>(hist, cutT);
  k_compact<<<dim3(nb, B), 256, 0, stream>>>(skey, cutT, cand, cnt, N);
  k_rank<<<dim3(CAP / 256, B), 256, 0, stream>>>(cand, cnt, sel);
  int off_scores = BK * 5, off_labels = BK * 6, off_keep = BK * 7;
  k_decode<<<(BK + 255) / 256, 256, 0, stream>>>(
      logits, deltas, anchors, sel, out, corners, areas, rad, validw, N, C,
      off_scores, off_labels, BK);
  k_prefilter<<<dim3(NPB, B), 256, 0, stream>>>(out, rad, areas, pairlist,
                                                segcnt);
  k_clip<<<(NSEG * 64 + 255) / 256, 256, 0, stream>>>(pairlist, segcnt,
                                                      corners, areas, sup,
                                                      NSEG);
  k_nms<<<B, 256, 0, stream>>>(sup, validw, out + off_keep);
}

// Round 6
// 161.535 us; speedup vs baseline: 1.3099x; 1.0369x over previous
//
#include <hip/hip_runtime.h>
#include <hip/hip_bf16.h>
#include <stdint.h>

typedef unsigned int u32;
typedef unsigned long long u64;

#define K_SEL 512
#define NBINS 4096
#define CAP 8192
#define SCORE_THR 0.05f
#define NMS_THR 0.5f
#define MAXROWS 512

__device__ __forceinline__ u32 fkey(float x) {
  u32 u = __float_as_uint(x);
  return u ^ ((u32)((int)u >> 31) | 0x80000000u);
}
__device__ __forceinline__ float fkey_inv(u32 k) {
  u32 u = (k & 0x80000000u) ? (k ^ 0x80000000u) : ~k;
  return __uint_as_float(u);
}

// K1a: per-anchor max logit -> sortable key (pure streaming, no histogram).
// Piggybacks the workspace zeroing (hist/cnt/sup) in its blockIdx.y==0 slice:
// rocclr's fillBufferAligned took 54 us for 192 KB (tiny-grid latency path).
__global__ __launch_bounds__(256) void k_max(const float* __restrict__ logits,
                                             u32* __restrict__ skey,
                                             float4* __restrict__ zbuf,
                                             int nz4, int N, int C) {
  if (blockIdx.y == 0) {
    for (int i = blockIdx.x * 256 + threadIdx.x; i < nz4;
         i += gridDim.x * 256)
      zbuf[i] = make_float4(0.f, 0.f, 0.f, 0.f);
  }
  int b = blockIdx.y;
  int n0 = blockIdx.x * MAXROWS;
  int nrow = min(MAXROWS, N - n0);
  __shared__ __align__(16) float tile[MAXROWS * 15];
  const float* src = logits + ((size_t)b * N + n0) * C;
  int tot = nrow * C;
  if (((tot & 3) == 0) && ((((size_t)src) & 15) == 0)) {
    const float4* s4 = (const float4*)src;
    float4* t4 = (float4*)tile;
    int n4 = tot >> 2;
    for (int i = threadIdx.x; i < n4; i += 256) t4[i] = s4[i];
  } else {
    for (int i = threadIdx.x; i < tot; i += 256) tile[i] = src[i];
  }
  __syncthreads();
  for (int r = threadIdx.x; r < nrow; r += 256) {
    const float* row = tile + r * 15;
    float mv = row[0];
    for (int c = 1; c < 15; c++) mv = fmaxf(mv, row[c]);
    skey[(size_t)b * N + n0 + r] = fkey(mv);
  }
}

// K1b: histogram of key top-12 bits (amortized LDS hist)
__global__ __launch_bounds__(256) void k_hist(const u32* __restrict__ skey,
                                              u32* __restrict__ hist, int N) {
  int b = blockIdx.y;
  __shared__ u32 sh[NBINS];
  for (int i = threadIdx.x; i < NBINS; i += 256) sh[i] = 0;
  __syncthreads();
  const u32* sb = skey + (size_t)b * N;
  for (int i = blockIdx.x * 256 + threadIdx.x; i < N; i += gridDim.x * 256)
    atomicAdd(&sh[sb[i] >> 20], 1u);
  __syncthreads();
  u32* hb = hist + (size_t)b * NBINS;
  for (int i = threadIdx.x; i < NBINS; i += 256) {
    u32 v = sh[i];
    if (v) atomicAdd(&hb[i], v);
  }
}

// K2: find cutoff bin T = max{bin : suffix_count(bin) >= K_SEL}
__global__ __launch_bounds__(256) void k_cutoff(const u32* __restrict__ hist,
                                                u32* __restrict__ cutT) {
  int b = blockIdx.x;
  int t = threadIdx.x;
  u32 h[16];
  u32 s = 0;
  const u32* hb = hist + (size_t)b * NBINS;
  for (int i = 0; i < 16; i++) { h[i] = hb[t * 16 + i]; s += h[i]; }
  __shared__ u32 cs[256];
  cs[t] = s;
  __syncthreads();
  for (int off = 1; off < 256; off <<= 1) {
    u32 add = (t + off < 256) ? cs[t + off] : 0;
    __syncthreads();
    cs[t] += add;
    __syncthreads();
  }
  u32 run = (t < 255) ? cs[t + 1] : 0;  // suffix over later chunks
  for (int i = 15; i >= 0; i--) {
    u32 sfx = run + h[i];
    if (run < (u32)K_SEL && sfx >= (u32)K_SEL) cutT[b] = (u32)(t * 16 + i);
    run = sfx;
  }
}

// K3: compact candidates with bin >= cutT
__global__ __launch_bounds__(256) void k_compact(
    const u32* __restrict__ skey, const u32* __restrict__ cutT,
    u64* __restrict__ cand, u32* __restrict__ cnt, int N) {
  int b = blockIdx.y;
  int n = blockIdx.x * 256 + threadIdx.x;
  if (n >= N) return;
  u32 key = skey[(size_t)b * N + n];
  if ((key >> 20) >= cutT[b]) {
    u32 pos = atomicAdd(&cnt[b], 1u);
    if (pos < CAP) cand[(size_t)b * CAP + pos] = ((u64)key << 32) | (u32)(~(u32)n);
  }
}

// K4: exact rank by counting (keys unique) -> sel[rank] for rank < K
__global__ __launch_bounds__(256) void k_rank(const u64* __restrict__ cand,
                                              const u32* __restrict__ cnt,
                                              u64* __restrict__ sel) {
  int b = blockIdx.y;
  int M = (int)min(cnt[b], (u32)CAP);
  if (blockIdx.x * 256 >= (u32)M) return;
  int m = blockIdx.x * 256 + threadIdx.x;
  u64 my = (m < M) ? cand[(size_t)b * CAP + m] : 0ull;
  int rank = 0;
  __shared__ u64 t[256];
  for (int j0 = 0; j0 < M; j0 += 256) {
    int j = j0 + threadIdx.x;
    t[threadIdx.x] = (j < M) ? cand[(size_t)b * CAP + j] : 0ull;
    __syncthreads();
    int lim = min(256, M - j0);
    for (int jj = 0; jj < lim; jj++) rank += (t[jj] > my) ? 1 : 0;
    __syncthreads();
  }
  if (m < M && rank < K_SEL) sel[b * K_SEL + rank] = my;
}

// K5: decode boxes, labels, scores, valid mask, corners/areas/radii
__global__ __launch_bounds__(256) void k_decode(
    const float* __restrict__ logits, const float* __restrict__ deltas,
    const float* __restrict__ anchors, const u64* __restrict__ sel,
    float* __restrict__ out, float* __restrict__ corners,
    float* __restrict__ areas, float* __restrict__ rad,
    u64* __restrict__ validw, int N, int C, int off_scores, int off_labels,
    int BK) {
  int g = blockIdx.x * 256 + threadIdx.x;
  if (g >= BK) return;
  int b = g >> 9;  // K_SEL == 512
  u64 s = sel[g];
  u32 key = (u32)(s >> 32);
  int idx = (int)(~(u32)s);
  float ml = fkey_inv(key);
  float score = 1.0f / (1.0f + expf(-ml));
  const float* lr = logits + ((size_t)b * N + idx) * C;
  float bv = lr[0];
  int lab = 0;
  for (int c = 1; c < C; c++) {
    float v = lr[c];
    if (v > bv) { bv = v; lab = c; }
  }
  const float* ar = anchors + (size_t)idx * 5;
  const float* dr = deltas + ((size_t)b * N + idx) * 5;
  float ax = ar[0], ay = ar[1], aw = ar[2], ah = ar[3], aa = ar[4];
  float dx = dr[0], dy = dr[1], dwv = dr[2], dhv = dr[3], da = dr[4];
  float px = ax + dx * aw;
  float py = ay + dy * ah;
  float pw = aw * expf(fminf(fmaxf(dwv, -4.0f), 4.0f));
  float ph = ah * expf(fminf(fmaxf(dhv, -4.0f), 4.0f));
  float pa = aa + da * 57.295779513082323f;
  float* ob = out + (size_t)g * 5;
  ob[0] = px; ob[1] = py; ob[2] = pw; ob[3] = ph; ob[4] = pa;
  out[off_scores + g] = score;
  out[off_labels + g] = (float)lab;
  bool valid = score > SCORE_THR;
  u64 bal = __ballot(valid);
  if ((threadIdx.x & 63) == 0) validw[g >> 6] = bal;
  float t = pa * 0.017453292519943295f;
  float cc = cosf(t), sn = sinf(t);
  float hx = pw * 0.5f, hy = ph * 0.5f;
  float* cp = corners + (size_t)g * 8;
  cp[0] = px + cc * (-hx) - sn * (-hy);
  cp[1] = py + sn * (-hx) + cc * (-hy);
  cp[2] = px + cc * (hx) - sn * (-hy);
  cp[3] = py + sn * (hx) + cc * (-hy);
  cp[4] = px + cc * (hx) - sn * (hy);
  cp[5] = py + sn * (hx) + cc * (hy);
  cp[6] = px + cc * (-hx) - sn * (hy);
  cp[7] = py + sn * (-hx) + cc * (hy);
  areas[g] = pw * ph;
  rad[g] = 0.5f * sqrtf(pw * pw + ph * ph);
}

// K6a: quick-reject all pairs, per-wave segment compaction (NO shared atomics)
__global__ __launch_bounds__(256) void k_prefilter(
    const float* __restrict__ boxes, const float* __restrict__ rad,
    const float* __restrict__ areas, u32* __restrict__ pairlist,
    u32* __restrict__ segcnt) {
  int b = blockIdx.y;
  int q = blockIdx.x * 256 + threadIdx.x;
  int i = q >> 9, j = q & (K_SEL - 1);
  bool ok = (j > i);
  if (ok) {
    int gi = b * K_SEL + i, gj = b * K_SEL + j;
    float ddx = boxes[(size_t)gi * 5 + 0] - boxes[(size_t)gj * 5 + 0];
    float ddy = boxes[(size_t)gi * 5 + 1] - boxes[(size_t)gj * 5 + 1];
    float rr = rad[gi] + rad[gj];
    float d2 = ddx * ddx + ddy * ddy;
    ok = !(d2 > rr * rr * 1.0001f);
    if (ok) {
      float ai = areas[gi], aj = areas[gj];
      float mnA = fminf(ai, aj), mxA = fmaxf(ai, aj);
      ok = !(2.0f * mnA < 0.999f * mxA);
    }
  }
  u64 m = __ballot(ok);
  int lane = threadIdx.x & 63;
  int wseg = ((b * gridDim.x + blockIdx.x) << 2) + (threadIdx.x >> 6);
  if (ok) {
    u32 r = (u32)__popcll(m & ((1ull << lane) - 1ull));
    pairlist[((size_t)wseg << 6) + r] = ((u32)b << 18) | ((u32)i << 9) | (u32)j;
  }
  if (lane == 0) segcnt[wseg] = (u32)__popcll(m);
}

// K6b: exact rotated IoU clip, one wave per survivor segment
__global__ __launch_bounds__(256) void k_clip(
    const u32* __restrict__ pairlist, const u32* __restrict__ segcnt,
    const float* __restrict__ corners, const float* __restrict__ areas,
    u64* __restrict__ sup, int nseg) {
  int wid = (blockIdx.x * 256 + threadIdx.x) >> 6;
  int lane = threadIdx.x & 63;
  if (wid >= nseg) return;
  u32 wcnt = segcnt[wid];
  if (wcnt == 0) return;  // wave-uniform early exit
  if (lane >= (int)wcnt) return;
  u32 pk = pairlist[((size_t)wid << 6) + lane];
  int b = (int)(pk >> 18);
  int i = (int)((pk >> 9) & 511u);
  int j = (int)(pk & 511u);
  int gi = b * K_SEL + i, gj = b * K_SEL + j;
  const float* ci = corners + (size_t)gi * 8;
  const float* cj = corners + (size_t)gj * 8;
  float X[8], Y[8], bx[4], by[4];
#pragma unroll
  for (int m = 0; m < 4; m++) {
    X[m] = ci[2 * m]; Y[m] = ci[2 * m + 1];
    X[m + 4] = 0.f; Y[m + 4] = 0.f;
    bx[m] = cj[2 * m]; by[m] = cj[2 * m + 1];
  }
  int cnt = 4;
#pragma unroll
  for (int e = 0; e < 4; e++) {
    float axp = bx[e], ayp = by[e];
    float ex = bx[(e + 1) & 3] - axp, ey = by[(e + 1) & 3] - ayp;
    float d[8];
#pragma unroll
    for (int m = 0; m < 8; m++)
      d[m] = ex * (Y[m] - ayp) - ey * (X[m] - axp);
    float NX[8], NY[8];
#pragma unroll
    for (int s = 0; s < 8; s++) { NX[s] = 0.f; NY[s] = 0.f; }
    int oc = 0;
#pragma unroll
    for (int m = 0; m < 8; m++) {
      bool act = (m < cnt);
      bool isLast = (m + 1 == cnt);
      float dn = isLast ? d[0] : d[(m + 1) & 7];
      float xn = isLast ? X[0] : X[(m + 1) & 7];
      float yn = isLast ? Y[0] : Y[(m + 1) & 7];
      bool cin = (d[m] >= 0.f), nin = (dn >= 0.f);
      bool e1 = act && cin;
      bool e2 = act && (cin != nin);
#pragma unroll
      for (int s = 0; s < 8; s++) {
        bool w = e1 && (oc == s);
        NX[s] = w ? X[m] : NX[s];
        NY[s] = w ? Y[m] : NY[s];
      }
      oc += e1 ? 1 : 0;
      float den = d[m] - dn;
      float dd = (fabsf(den) < 1e-9f) ? 1e-9f : den;
      float tt = d[m] / dd;
      float ix = X[m] + tt * (xn - X[m]);
      float iy = Y[m] + tt * (yn - Y[m]);
#pragma unroll
      for (int s = 0; s < 8; s++) {
        bool w = e2 && (oc == s);
        NX[s] = w ? ix : NX[s];
        NY[s] = w ? iy : NY[s];
      }
      oc += e2 ? 1 : 0;
    }
    cnt = oc;
#pragma unroll
    for (int m = 0; m < 8; m++) { X[m] = NX[m]; Y[m] = NY[m]; }
  }
  float sum = 0.f;
#pragma unroll
  for (int m = 0; m < 8; m++) {
    bool act = (m < cnt);
    bool isLast = (m + 1 == cnt);
    float xn = isLast ? X[0] : X[(m + 1) & 7];
    float yn = isLast ? Y[0] : Y[(m + 1) & 7];
    float cr = X[m] * yn - Y[m] * xn;
    sum += act ? cr : 0.f;
  }
  float inter = (cnt >= 3) ? 0.5f * fabsf(sum) : 0.f;
  float ai = areas[gi], aj = areas[gj];
  float uni = ai + aj - inter;
  float iou = inter / fmaxf(uni, 1e-6f);
  if (iou > NMS_THR)
    atomicOr(&sup[((size_t)b * K_SEL + i) * 8 + (j >> 6)], 1ull << (j & 63));
}

// K7: sequential NMS sweep, replicated 512-bit state in registers, no shuffles
#define GLUE2(a, b) a##b
#define GLUE(a, b) GLUE2(a, b)

#define NMS_STEP(BUF, Ii, cc)                                              \
  {                                                                        \
    int bit_ = (Ii) & 63;                                                  \
    u64 live_ = ((vv >> bit_) & ~(rw >> bit_)) & 1ull;                     \
    u64 m_ = (u64)0 - live_;                                               \
    rem0 |= GLUE(BUF, 0) & m_; rem1 |= GLUE(BUF, 1) & m_;                  \
    rem2 |= GLUE(BUF, 2) & m_; rem3 |= GLUE(BUF, 3) & m_;                  \
    rem4 |= GLUE(BUF, 4) & m_; rem5 |= GLUE(BUF, 5) & m_;                  \
    rem6 |= GLUE(BUF, 6) & m_; rem7 |= GLUE(BUF, 7) & m_;                  \
    rw |= GLUE(BUF, cc) & m_;                                              \
    km |= live_ << bit_;                                                   \
    int pr_ = ((Ii) + 4) & (K_SEL - 1);                                    \
    GLUE(BUF, 0) = ls[pr_ * 8 + 0]; GLUE(BUF, 1) = ls[pr_ * 8 + 1];        \
    GLUE(BUF, 2) = ls[pr_ * 8 + 2]; GLUE(BUF, 3) = ls[pr_ * 8 + 3];        \
    GLUE(BUF, 4) = ls[pr_ * 8 + 4]; GLUE(BUF, 5) = ls[pr_ * 8 + 5];        \
    GLUE(BUF, 6) = ls[pr_ * 8 + 6]; GLUE(BUF, 7) = ls[pr_ * 8 + 7];        \
  }

#define NMS_CHUNK(cc)                                                      \
  {                                                                        \
    u64 vv = GLUE(va, cc);                                                 \
    u64 rw = GLUE(rem, cc);                                                \
    u64 km = 0;                                                            \
    for (int g = 0; g < 16; ++g) {                                         \
      int i0 = (cc)*64 + g * 4;                                            \
      NMS_STEP(A, i0 + 0, cc)                                              \
      NMS_STEP(B, i0 + 1, cc)                                              \
      NMS_STEP(C, i0 + 2, cc)                                              \
      NMS_STEP(D, i0 + 3, cc)                                              \
    }                                                                      \
    ko[(cc)*64 + lane] = (float)((km >> lane) & 1ull);                     \
  }

__global__ __launch_bounds__(256) void k_nms(const u64* __restrict__ sup,
                                             const u64* __restrict__ validw,
                                             float* __restrict__ keep_out) {
  int b = blockIdx.x;
  __shared__ u64 ls[K_SEL * 8];
  const u64* sb = sup + (size_t)b * K_SEL * 8;
  {
    const ulonglong2* s2 = (const ulonglong2*)sb;
    ulonglong2* l2 = (ulonglong2*)ls;
    for (int k = threadIdx.x; k < K_SEL * 4; k += 256) l2[k] = s2[k];
  }
  __syncthreads();
  if (threadIdx.x >= 64) return;
  int lane = threadIdx.x;
  const u64* vb = validw + (size_t)b * 8;
  u64 va0 = vb[0], va1 = vb[1], va2 = vb[2], va3 = vb[3];
  u64 va4 = vb[4], va5 = vb[5], va6 = vb[6], va7 = vb[7];
  u64 rem0 = 0, rem1 = 0, rem2 = 0, rem3 = 0;
  u64 rem4 = 0, rem5 = 0, rem6 = 0, rem7 = 0;
  u64 A0 = ls[0], A1 = ls[1], A2 = ls[2], A3 = ls[3];
  u64 A4 = ls[4], A5 = ls[5], A6 = ls[6], A7 = ls[7];
  u64 B0 = ls[8], B1 = ls[9], B2 = ls[10], B3 = ls[11];
  u64 B4 = ls[12], B5 = ls[13], B6 = ls[14], B7 = ls[15];
  u64 C0 = ls[16], C1 = ls[17], C2 = ls[18], C3 = ls[19];
  u64 C4 = ls[20], C5 = ls[21], C6 = ls[22], C7 = ls[23];
  u64 D0 = ls[24], D1 = ls[25], D2 = ls[26], D3 = ls[27];
  u64 D4 = ls[28], D5 = ls[29], D6 = ls[30], D7 = ls[31];
  float* ko = keep_out + b * K_SEL;
  NMS_CHUNK(0)
  NMS_CHUNK(1)
  NMS_CHUNK(2)
  NMS_CHUNK(3)
  NMS_CHUNK(4)
  NMS_CHUNK(5)
  NMS_CHUNK(6)
  NMS_CHUNK(7)
}

extern "C" void kernel_launch(void* const* d_in, const int* in_sizes, int n_in,
                              void* d_out, int out_size, void* d_ws,
                              size_t ws_size, hipStream_t stream) {
  const float* logits = (const float*)d_in[0];
  const float* deltas = (const float*)d_in[1];
  const float* anchors = (const float*)d_in[2];
  float* out = (float*)d_out;
  int N = in_sizes[2] / 5;
  int B = in_sizes[1] / (N * 5);
  int C = (int)((long long)in_sizes[0] / ((long long)B * N));
  int BK = B * K_SEL;
  int NPB = K_SEL * K_SEL / 256;      // pair-blocks per image
  int NSEG = B * NPB * 4;             // one segment per wave

  char* ws = (char*)d_ws;
  size_t o_hist = 0;
  size_t o_cnt = o_hist + (size_t)B * NBINS * 4;
  size_t o_sup = o_cnt + 256;
  size_t zero_end = o_sup + (size_t)B * K_SEL * 8 * 8;
  size_t o_cut = (zero_end + 255) & ~(size_t)255;
  size_t o_skey = (o_cut + 256 + 255) & ~(size_t)255;
  size_t o_cand = (o_skey + (size_t)B * N * 4 + 255) & ~(size_t)255;
  size_t o_sel = (o_cand + (size_t)B * CAP * 8 + 255) & ~(size_t)255;
  size_t o_vw = (o_sel + (size_t)BK * 8 + 255) & ~(size_t)255;
  size_t o_corn = (o_vw + (size_t)B * 8 * 8 + 255) & ~(size_t)255;
  size_t o_area = (o_corn + (size_t)BK * 8 * 4 + 255) & ~(size_t)255;
  size_t o_rad = (o_area + (size_t)BK * 4 + 255) & ~(size_t)255;
  size_t o_segc = (o_rad + (size_t)BK * 4 + 255) & ~(size_t)255;
  size_t o_pair = (o_segc + (size_t)NSEG * 4 + 255) & ~(size_t)255;

  u32* hist = (u32*)(ws + o_hist);
  u32* cnt = (u32*)(ws + o_cnt);
  u32* cutT = (u32*)(ws + o_cut);
  u64* sup = (u64*)(ws + o_sup);
  u32* skey = (u32*)(ws + o_skey);
  u64* cand = (u64*)(ws + o_cand);
  u64* sel = (u64*)(ws + o_sel);
  u64* validw = (u64*)(ws + o_vw);
  float* corners = (float*)(ws + o_corn);
  float* areas = (float*)(ws + o_area);
  float* rad = (float*)(ws + o_rad);
  u32* segcnt = (u32*)(ws + o_segc);
  u32* pairlist = (u32*)(ws + o_pair);

  int nz4 = (int)(zero_end >> 4);  // zero region is 16B-aligned by layout

  int nbm = (N + MAXROWS - 1) / MAXROWS;
  int nb = (N + 255) / 256;
  k_max<<<dim3(nbm, B), 256, 0, stream>>>(logits, skey, (float4*)ws, nz4, N, C);
  k_hist<<<dim3(128, B), 256, 0, stream>>>(skey, hist, N);
  k_cutoff<<<B, 256, 0, stream>>>(hist, cutT);
  k_compact<<<dim3(nb, B), 256, 0, stream>>>(skey, cutT, cand, cnt, N);
  k_rank<<<dim3(CAP / 256, B), 256, 0, stream>>>(cand, cnt, sel);
  int off_scores = BK * 5, off_labels = BK * 6, off_keep = BK * 7;
  k_decode<<<(BK + 255) / 256, 256, 0, stream>>>(
      logits, deltas, anchors, sel, out, corners, areas, rad, validw, N, C,
      off_scores, off_labels, BK);
  k_prefilter<<<dim3(NPB, B), 256, 0, stream>>>(out, rad, areas, pairlist,
                                                segcnt);
  k_clip<<<(NSEG * 64 + 255) / 256, 256, 0, stream>>>(pairlist, segcnt,
                                                      corners, areas, sup,
                                                      NSEG);
  k_nms<<<B, 256, 0, stream>>>(sup, validw, out + off_keep);
}

// Round 7
// 153.257 us; speedup vs baseline: 1.3806x; 1.0540x over previous
//
#include <hip/hip_runtime.h>
#include <hip/hip_bf16.h>
#include <stdint.h>

typedef unsigned int u32;
typedef unsigned long long u64;

#define K_SEL 512
#define NBINS 4096
#define CAP 8192
#define SCORE_THR 0.05f
#define NMS_THR 0.5f
#define MAXROWS 256
#define PF_SLOTS 2048

__device__ __forceinline__ u32 fkey(float x) {
  u32 u = __float_as_uint(x);
  return u ^ ((u32)((int)u >> 31) | 0x80000000u);
}
__device__ __forceinline__ float fkey_inv(u32 k) {
  u32 u = (k & 0x80000000u) ? (k ^ 0x80000000u) : ~k;
  return __uint_as_float(u);
}

// K1: per-anchor max logit -> sortable key. 15KB LDS tile -> 8 blocks/CU
// (100% occupancy). Piggybacks workspace zeroing in blockIdx.y==0 slice.
__global__ __launch_bounds__(256) void k_max(const float* __restrict__ logits,
                                             u32* __restrict__ skey,
                                             float4* __restrict__ zbuf,
                                             int nz4, int N, int C) {
  if (blockIdx.y == 0) {
    for (int i = blockIdx.x * 256 + threadIdx.x; i < nz4;
         i += gridDim.x * 256)
      zbuf[i] = make_float4(0.f, 0.f, 0.f, 0.f);
  }
  int b = blockIdx.y;
  int n0 = blockIdx.x * MAXROWS;
  int nrow = min(MAXROWS, N - n0);
  __shared__ __align__(16) float tile[MAXROWS * 15];
  const float* src = logits + ((size_t)b * N + n0) * C;
  int tot = nrow * C;
  if (((tot & 3) == 0) && ((((size_t)src) & 15) == 0)) {
    const float4* s4 = (const float4*)src;
    float4* t4 = (float4*)tile;
    int n4 = tot >> 2;
    for (int i = threadIdx.x; i < n4; i += 256) t4[i] = s4[i];
  } else {
    for (int i = threadIdx.x; i < tot; i += 256) tile[i] = src[i];
  }
  __syncthreads();
  int r = threadIdx.x;
  if (r < nrow) {
    const float* row = tile + r * 15;
    float mv = row[0];
    for (int c = 1; c < 15; c++) mv = fmaxf(mv, row[c]);
    skey[(size_t)b * N + n0 + r] = fkey(mv);
  }
}

// K2: histogram of key top-12 bits; the LAST block per image (done-counter)
// also computes the cutoff bin T = max{bin : suffix_count(bin) >= K_SEL}.
__global__ __launch_bounds__(256) void k_hist(const u32* __restrict__ skey,
                                              u32* __restrict__ hist,
                                              u32* __restrict__ done,
                                              u32* __restrict__ cutT, int N) {
  int b = blockIdx.y;
  __shared__ u32 sh[NBINS];
  for (int i = threadIdx.x; i < NBINS; i += 256) sh[i] = 0;
  __syncthreads();
  const u32* sb = skey + (size_t)b * N;
  for (int i = blockIdx.x * 256 + threadIdx.x; i < N; i += gridDim.x * 256)
    atomicAdd(&sh[sb[i] >> 20], 1u);
  __syncthreads();
  u32* hb = hist + (size_t)b * NBINS;
  for (int i = threadIdx.x; i < NBINS; i += 256) {
    u32 v = sh[i];
    if (v) atomicAdd(&hb[i], v);
  }
  __threadfence();
  __shared__ u32 lastflag;
  if (threadIdx.x == 0) lastflag = atomicAdd(&done[b], 1u);
  __syncthreads();
  if (lastflag != gridDim.x - 1) return;
  // last block for image b: compute cutoff (device-scope atomic reads of hist)
  int t = threadIdx.x;
  u32 h[16];
  u32 s = 0;
  for (int i = 0; i < 16; i++) {
    h[i] = atomicOr(&hb[t * 16 + i], 0u);
    s += h[i];
  }
  __shared__ u32 cs[256];
  cs[t] = s;
  __syncthreads();
  for (int off = 1; off < 256; off <<= 1) {
    u32 add = (t + off < 256) ? cs[t + off] : 0;
    __syncthreads();
    cs[t] += add;
    __syncthreads();
  }
  u32 run = (t < 255) ? cs[t + 1] : 0;
  for (int i = 15; i >= 0; i--) {
    u32 sfx = run + h[i];
    if (run < (u32)K_SEL && sfx >= (u32)K_SEL) cutT[b] = (u32)(t * 16 + i);
    run = sfx;
  }
}

// K3: compact candidates with bin >= cutT
__global__ __launch_bounds__(256) void k_compact(
    const u32* __restrict__ skey, const u32* __restrict__ cutT,
    u64* __restrict__ cand, u32* __restrict__ cnt, int N) {
  int b = blockIdx.y;
  int n = blockIdx.x * 256 + threadIdx.x;
  if (n >= N) return;
  u32 key = skey[(size_t)b * N + n];
  if ((key >> 20) >= cutT[b]) {
    u32 pos = atomicAdd(&cnt[b], 1u);
    if (pos < CAP) cand[(size_t)b * CAP + pos] = ((u64)key << 32) | (u32)(~(u32)n);
  }
}

// K4: rank by counting (keys unique), then decode in-place for rank < K_SEL.
__global__ __launch_bounds__(256) void k_rankdecode(
    const u64* __restrict__ cand, const u32* __restrict__ cnt,
    const float* __restrict__ logits, const float* __restrict__ deltas,
    const float* __restrict__ anchors, float* __restrict__ out,
    float* __restrict__ corners, float* __restrict__ areas,
    float* __restrict__ rad, u64* __restrict__ validw, int N, int C,
    int off_scores, int off_labels) {
  int b = blockIdx.y;
  int M = (int)min(cnt[b], (u32)CAP);
  if (blockIdx.x * 256 >= (u32)M) return;
  int m = blockIdx.x * 256 + threadIdx.x;
  u64 my = (m < M) ? cand[(size_t)b * CAP + m] : 0ull;
  int rank = 0;
  __shared__ u64 t[256];
  for (int j0 = 0; j0 < M; j0 += 256) {
    int j = j0 + threadIdx.x;
    t[threadIdx.x] = (j < M) ? cand[(size_t)b * CAP + j] : 0ull;
    __syncthreads();
    int lim = min(256, M - j0);
    for (int jj = 0; jj < lim; jj++) rank += (t[jj] > my) ? 1 : 0;
    __syncthreads();
  }
  if (m >= M || rank >= K_SEL) return;
  int g = b * K_SEL + rank;
  u32 key = (u32)(my >> 32);
  int idx = (int)(~(u32)my);
  float ml = fkey_inv(key);
  float score = 1.0f / (1.0f + expf(-ml));
  const float* lr = logits + ((size_t)b * N + idx) * C;
  float bv = lr[0];
  int lab = 0;
  for (int c = 1; c < C; c++) {
    float v = lr[c];
    if (v > bv) { bv = v; lab = c; }
  }
  const float* ar = anchors + (size_t)idx * 5;
  const float* dr = deltas + ((size_t)b * N + idx) * 5;
  float ax = ar[0], ay = ar[1], aw = ar[2], ah = ar[3], aa = ar[4];
  float dx = dr[0], dy = dr[1], dwv = dr[2], dhv = dr[3], da = dr[4];
  float px = ax + dx * aw;
  float py = ay + dy * ah;
  float pw = aw * expf(fminf(fmaxf(dwv, -4.0f), 4.0f));
  float ph = ah * expf(fminf(fmaxf(dhv, -4.0f), 4.0f));
  float pa = aa + da * 57.295779513082323f;
  float* ob = out + (size_t)g * 5;
  ob[0] = px; ob[1] = py; ob[2] = pw; ob[3] = ph; ob[4] = pa;
  out[off_scores + g] = score;
  out[off_labels + g] = (float)lab;
  if (score > SCORE_THR) atomicOr(&validw[g >> 6], 1ull << (g & 63));
  float tt = pa * 0.017453292519943295f;
  float cc = cosf(tt), sn = sinf(tt);
  float hx = pw * 0.5f, hy = ph * 0.5f;
  float* cp = corners + (size_t)g * 8;
  cp[0] = px + cc * (-hx) - sn * (-hy);
  cp[1] = py + sn * (-hx) + cc * (-hy);
  cp[2] = px + cc * (hx) - sn * (-hy);
  cp[3] = py + sn * (hx) + cc * (-hy);
  cp[4] = px + cc * (hx) - sn * (hy);
  cp[5] = py + sn * (hx) + cc * (hy);
  cp[6] = px + cc * (-hx) - sn * (hy);
  cp[7] = py + sn * (-hx) + cc * (hy);
  areas[g] = pw * ph;
  rad[g] = 0.5f * sqrtf(pw * pw + ph * ph);
}

// K5: fused prefilter + exact clip. Block covers 2048 pair-slots of one image;
// j-side (cx,cy,rad,area) staged in LDS; survivors pushed to an LDS worklist,
// then clipped block-locally (exact reference clip arithmetic).
__global__ __launch_bounds__(256) void k_pairclip(
    const float* __restrict__ out, const float* __restrict__ corners,
    const float* __restrict__ areas, const float* __restrict__ rad,
    u64* __restrict__ sup) {
  int q0 = blockIdx.x * PF_SLOTS;
  int b = q0 >> 18;             // 512*512 slots per image
  int qi = q0 & (262143);
  __shared__ float4 js[K_SEL];
  __shared__ u32 list[PF_SLOTS];
  __shared__ u32 lcnt;
  if (threadIdx.x == 0) lcnt = 0;
  for (int j = threadIdx.x; j < K_SEL; j += 256) {
    int gj = b * K_SEL + j;
    js[j] = make_float4(out[(size_t)gj * 5 + 0], out[(size_t)gj * 5 + 1],
                        rad[gj], areas[gj]);
  }
  __syncthreads();
  int qq = qi + threadIdx.x * 8;
  int i = qq >> 9;
  int j0 = qq & 511;
  int gi = b * K_SEL + i;
  float cxi = out[(size_t)gi * 5 + 0], cyi = out[(size_t)gi * 5 + 1];
  float ri = rad[gi], ai = areas[gi];
#pragma unroll
  for (int k = 0; k < 8; k++) {
    int j = j0 + k;
    if (j <= i) continue;
    float4 J = js[j];
    float ddx = cxi - J.x, ddy = cyi - J.y;
    float rr = ri + J.z;
    float d2 = ddx * ddx + ddy * ddy;
    if (d2 > rr * rr * 1.0001f) continue;
    float mnA = fminf(ai, J.w), mxA = fmaxf(ai, J.w);
    if (2.0f * mnA < 0.999f * mxA) continue;
    u32 p = atomicAdd(&lcnt, 1u);
    list[p] = ((u32)i << 9) | (u32)j;
  }
  __syncthreads();
  u32 M = lcnt;
  for (u32 l = threadIdx.x; l < M; l += 256) {
    u32 pk = list[l];
    int i2 = (int)(pk >> 9);
    int j2 = (int)(pk & 511u);
    int gi2 = b * K_SEL + i2, gj2 = b * K_SEL + j2;
    const float* ci = corners + (size_t)gi2 * 8;
    const float* cj = corners + (size_t)gj2 * 8;
    float X[8], Y[8], bx[4], by[4];
#pragma unroll
    for (int m = 0; m < 4; m++) {
      X[m] = ci[2 * m]; Y[m] = ci[2 * m + 1];
      X[m + 4] = 0.f; Y[m + 4] = 0.f;
      bx[m] = cj[2 * m]; by[m] = cj[2 * m + 1];
    }
    int cnt = 4;
#pragma unroll
    for (int e = 0; e < 4; e++) {
      float axp = bx[e], ayp = by[e];
      float ex = bx[(e + 1) & 3] - axp, ey = by[(e + 1) & 3] - ayp;
      float d[8];
#pragma unroll
      for (int m = 0; m < 8; m++)
        d[m] = ex * (Y[m] - ayp) - ey * (X[m] - axp);
      float NX[8], NY[8];
#pragma unroll
      for (int s = 0; s < 8; s++) { NX[s] = 0.f; NY[s] = 0.f; }
      int oc = 0;
#pragma unroll
      for (int m = 0; m < 8; m++) {
        bool act = (m < cnt);
        bool isLast = (m + 1 == cnt);
        float dn = isLast ? d[0] : d[(m + 1) & 7];
        float xn = isLast ? X[0] : X[(m + 1) & 7];
        float yn = isLast ? Y[0] : Y[(m + 1) & 7];
        bool cin = (d[m] >= 0.f), nin = (dn >= 0.f);
        bool e1 = act && cin;
        bool e2 = act && (cin != nin);
#pragma unroll
        for (int s = 0; s < 8; s++) {
          bool w = e1 && (oc == s);
          NX[s] = w ? X[m] : NX[s];
          NY[s] = w ? Y[m] : NY[s];
        }
        oc += e1 ? 1 : 0;
        float den = d[m] - dn;
        float dd = (fabsf(den) < 1e-9f) ? 1e-9f : den;
        float tt = d[m] / dd;
        float ix = X[m] + tt * (xn - X[m]);
        float iy = Y[m] + tt * (yn - Y[m]);
#pragma unroll
        for (int s = 0; s < 8; s++) {
          bool w = e2 && (oc == s);
          NX[s] = w ? ix : NX[s];
          NY[s] = w ? iy : NY[s];
        }
        oc += e2 ? 1 : 0;
      }
      cnt = oc;
#pragma unroll
      for (int m = 0; m < 8; m++) { X[m] = NX[m]; Y[m] = NY[m]; }
    }
    float sum = 0.f;
#pragma unroll
    for (int m = 0; m < 8; m++) {
      bool act = (m < cnt);
      bool isLast = (m + 1 == cnt);
      float xn = isLast ? X[0] : X[(m + 1) & 7];
      float yn = isLast ? Y[0] : Y[(m + 1) & 7];
      float cr = X[m] * yn - Y[m] * xn;
      sum += act ? cr : 0.f;
    }
    float inter = (cnt >= 3) ? 0.5f * fabsf(sum) : 0.f;
    float ai2 = areas[gi2], aj2 = areas[gj2];
    float uni = ai2 + aj2 - inter;
    float iou = inter / fmaxf(uni, 1e-6f);
    if (iou > NMS_THR)
      atomicOr(&sup[((size_t)b * K_SEL + i2) * 8 + (j2 >> 6)],
               1ull << (j2 & 63));
  }
}

// K6: sequential NMS sweep, replicated 512-bit state in registers, no shuffles
#define GLUE2(a, b) a##b
#define GLUE(a, b) GLUE2(a, b)

#define NMS_STEP(BUF, Ii, cc)                                              \
  {                                                                        \
    int bit_ = (Ii) & 63;                                                  \
    u64 live_ = ((vv >> bit_) & ~(rw >> bit_)) & 1ull;                     \
    u64 m_ = (u64)0 - live_;                                               \
    rem0 |= GLUE(BUF, 0) & m_; rem1 |= GLUE(BUF, 1) & m_;                  \
    rem2 |= GLUE(BUF, 2) & m_; rem3 |= GLUE(BUF, 3) & m_;                  \
    rem4 |= GLUE(BUF, 4) & m_; rem5 |= GLUE(BUF, 5) & m_;                  \
    rem6 |= GLUE(BUF, 6) & m_; rem7 |= GLUE(BUF, 7) & m_;                  \
    rw |= GLUE(BUF, cc) & m_;                                              \
    km |= live_ << bit_;                                                   \
    int pr_ = ((Ii) + 4) & (K_SEL - 1);                                    \
    GLUE(BUF, 0) = ls[pr_ * 8 + 0]; GLUE(BUF, 1) = ls[pr_ * 8 + 1];        \
    GLUE(BUF, 2) = ls[pr_ * 8 + 2]; GLUE(BUF, 3) = ls[pr_ * 8 + 3];        \
    GLUE(BUF, 4) = ls[pr_ * 8 + 4]; GLUE(BUF, 5) = ls[pr_ * 8 + 5];        \
    GLUE(BUF, 6) = ls[pr_ * 8 + 6]; GLUE(BUF, 7) = ls[pr_ * 8 + 7];        \
  }

#define NMS_CHUNK(cc)                                                      \
  {                                                                        \
    u64 vv = GLUE(va, cc);                                                 \
    u64 rw = GLUE(rem, cc);                                                \
    u64 km = 0;                                                            \
    for (int g = 0; g < 16; ++g) {                                         \
      int i0 = (cc)*64 + g * 4;                                            \
      NMS_STEP(A, i0 + 0, cc)                                              \
      NMS_STEP(B, i0 + 1, cc)                                              \
      NMS_STEP(C, i0 + 2, cc)                                              \
      NMS_STEP(D, i0 + 3, cc)                                              \
    }                                                                      \
    ko[(cc)*64 + lane] = (float)((km >> lane) & 1ull);                     \
  }

__global__ __launch_bounds__(256) void k_nms(const u64* __restrict__ sup,
                                             const u64* __restrict__ validw,
                                             float* __restrict__ keep_out) {
  int b = blockIdx.x;
  __shared__ u64 ls[K_SEL * 8];
  const u64* sb = sup + (size_t)b * K_SEL * 8;
  {
    const ulonglong2* s2 = (const ulonglong2*)sb;
    ulonglong2* l2 = (ulonglong2*)ls;
    for (int k = threadIdx.x; k < K_SEL * 4; k += 256) l2[k] = s2[k];
  }
  __syncthreads();
  if (threadIdx.x >= 64) return;
  int lane = threadIdx.x;
  const u64* vb = validw + (size_t)b * 8;
  u64 va0 = vb[0], va1 = vb[1], va2 = vb[2], va3 = vb[3];
  u64 va4 = vb[4], va5 = vb[5], va6 = vb[6], va7 = vb[7];
  u64 rem0 = 0, rem1 = 0, rem2 = 0, rem3 = 0;
  u64 rem4 = 0, rem5 = 0, rem6 = 0, rem7 = 0;
  u64 A0 = ls[0], A1 = ls[1], A2 = ls[2], A3 = ls[3];
  u64 A4 = ls[4], A5 = ls[5], A6 = ls[6], A7 = ls[7];
  u64 B0 = ls[8], B1 = ls[9], B2 = ls[10], B3 = ls[11];
  u64 B4 = ls[12], B5 = ls[13], B6 = ls[14], B7 = ls[15];
  u64 C0 = ls[16], C1 = ls[17], C2 = ls[18], C3 = ls[19];
  u64 C4 = ls[20], C5 = ls[21], C6 = ls[22], C7 = ls[23];
  u64 D0 = ls[24], D1 = ls[25], D2 = ls[26], D3 = ls[27];
  u64 D4 = ls[28], D5 = ls[29], D6 = ls[30], D7 = ls[31];
  float* ko = keep_out + b * K_SEL;
  NMS_CHUNK(0)
  NMS_CHUNK(1)
  NMS_CHUNK(2)
  NMS_CHUNK(3)
  NMS_CHUNK(4)
  NMS_CHUNK(5)
  NMS_CHUNK(6)
  NMS_CHUNK(7)
}

extern "C" void kernel_launch(void* const* d_in, const int* in_sizes, int n_in,
                              void* d_out, int out_size, void* d_ws,
                              size_t ws_size, hipStream_t stream) {
  const float* logits = (const float*)d_in[0];
  const float* deltas = (const float*)d_in[1];
  const float* anchors = (const float*)d_in[2];
  float* out = (float*)d_out;
  int N = in_sizes[2] / 5;
  int B = in_sizes[1] / (N * 5);
  int C = (int)((long long)in_sizes[0] / ((long long)B * N));
  int BK = B * K_SEL;

  char* ws = (char*)d_ws;
  // zeroed region (contiguous, 16B-aligned total): hist, cnt, done, validw, sup
  size_t o_hist = 0;                                   // B*NBINS*4 = 64 KB
  size_t o_cnt = o_hist + (size_t)B * NBINS * 4;       // 256 B slot
  size_t o_done = o_cnt + 256;                         // 256 B slot
  size_t o_vw = o_done + 256;                          // B*8*8 = 256 B
  size_t o_sup = o_vw + 256;                           // B*K_SEL*8*8 = 128 KB
  size_t zero_end = o_sup + (size_t)B * K_SEL * 8 * 8;
  size_t o_cut = (zero_end + 255) & ~(size_t)255;
  size_t o_skey = (o_cut + 256 + 255) & ~(size_t)255;
  size_t o_cand = (o_skey + (size_t)B * N * 4 + 255) & ~(size_t)255;
  size_t o_corn = (o_cand + (size_t)B * CAP * 8 + 255) & ~(size_t)255;
  size_t o_area = (o_corn + (size_t)BK * 8 * 4 + 255) & ~(size_t)255;
  size_t o_rad = (o_area + (size_t)BK * 4 + 255) & ~(size_t)255;

  u32* hist = (u32*)(ws + o_hist);
  u32* cnt = (u32*)(ws + o_cnt);
  u32* done = (u32*)(ws + o_done);
  u64* validw = (u64*)(ws + o_vw);
  u64* sup = (u64*)(ws + o_sup);
  u32* cutT = (u32*)(ws + o_cut);
  u32* skey = (u32*)(ws + o_skey);
  u64* cand = (u64*)(ws + o_cand);
  float* corners = (float*)(ws + o_corn);
  float* areas = (float*)(ws + o_area);
  float* rad = (float*)(ws + o_rad);

  int nz4 = (int)(zero_end >> 4);

  int nbm = (N + MAXROWS - 1) / MAXROWS;
  int nb = (N + 255) / 256;
  k_max<<<dim3(nbm, B), 256, 0, stream>>>(logits, skey, (float4*)ws, nz4, N, C);
  k_hist<<<dim3(128, B), 256, 0, stream>>>(skey, hist, done, cutT, N);
  k_compact<<<dim3(nb, B), 256, 0, stream>>>(skey, cutT, cand, cnt, N);
  int off_scores = BK * 5, off_labels = BK * 6, off_keep = BK * 7;
  k_rankdecode<<<dim3(CAP / 256, B), 256, 0, stream>>>(
      cand, cnt, logits, deltas, anchors, out, corners, areas, rad, validw, N,
      C, off_scores, off_labels);
  k_pairclip<<<B * K_SEL * K_SEL / PF_SLOTS, 256, 0, stream>>>(
      out, corners, areas, rad, sup);
  k_nms<<<B, 256, 0, stream>>>(sup, validw, out + off_keep);
}